// Round 11
// baseline (38.317 us; speedup 1.0000x reference)
//
#include <hip/hip_runtime.h>

// MixtureOfExpertsNet: B=8388608 rows, E=4, H=16. f32 in/out.
// pred = sum_e(p_e*m_e*adj_e) / sum_e(p_e*m_e)  (softmax max-sub and /wsum cancel)
//
// R10 proved the 58-74us plateau was VALU inst count: PWL-LUT body (~80
// slots/row) dropped 59.3 -> 35.6us. adj_e(x) is 1-D piecewise-linear ->
// 1024-bin midpoint-anchored (slope,intercept) LUT over [-8,8].
// R11: trim non-streaming overhead: RPT=16 (halves per-block LUT staging,
// 134->67MB L2 traffic), gating consts pre-scaled by log2e in prep (saves
// 4 v_mul/row; read as uniform s_loads), nontemporal stores (write-once
// stream; preserve x's L3 residency). Body unchanged.

typedef float f32x2 __attribute__((ext_vector_type(2)));
typedef float f32x4 __attribute__((ext_vector_type(4)));

#define RPT   16
#define BINS  1024
#define XLO   -8.0f
#define SCALE 64.0f          // BINS / 16

// one thread per (e, bin): m = sum_{h active at bin center} w1*w2,
//                          c = b2 + sum_{h active} b1*w2
// block 0 threads 0..19 additionally write log2e-scaled gating consts.
__global__ __launch_bounds__(256) void prep_kernel(
    const float* __restrict__ Wg, const float* __restrict__ bg,
    const float* __restrict__ W1, const float* __restrict__ b1,
    const float* __restrict__ W2, const float* __restrict__ b2,
    f32x2* __restrict__ lut)      // [e*BINS + bin], then 16 wgl + 4 bgl floats
{
    int i = blockIdx.x * blockDim.x + threadIdx.x;   // 0 .. 4*BINS-1
    if (i >= 4 * BINS) return;
    int e = i >> 10, bin = i & (BINS - 1);
    float xc = ((float)bin + 0.5f) * (1.0f / SCALE) + XLO;   // bin midpoint
    float m = 0.0f, c = b2[e];
    for (int h = 0; h < 16; ++h) {
        float w1 = W1[e * 16 + h], bb = b1[e * 16 + h], w2 = W2[e * 16 + h];
        bool active = (fmaf(w1, xc, bb) > 0.0f);     // w1==0 case falls out
        m += active ? w1 * w2 : 0.0f;
        c += active ? bb * w2 : 0.0f;
    }
    lut[e * BINS + bin] = (f32x2){m, c};

    const float L2E = 1.4426950408889634f;
    float* gp = (float*)(lut + 4 * BINS);
    if (i < 16) gp[i] = Wg[i] * L2E;                 // wgl[e*4+j]
    else if (i < 20) gp[i] = bg[i - 16] * L2E;       // bgl[e]
}

__global__ __launch_bounds__(256, 4) void moe_kernel(
    const f32x4* __restrict__ x, const f32x2* __restrict__ lutg,
    float* __restrict__ out)
{
    __shared__ f32x2 lut[4 * BINS];                  // 32 KB
    const int t = threadIdx.x;
    const int base = blockIdx.x * (256 * RPT) + t;
    const float* gp = (const float*)(lutg + 4 * BINS);  // uniform -> s_load

    // issue all row loads first; latency hides under LUT staging + barrier
    f32x4 xv[RPT];
#pragma unroll
    for (int k = 0; k < RPT; ++k)
        xv[k] = x[base + k * 256];

    // stage LUT (32KB, L2-resident) to LDS, coalesced
    {
        const f32x4* src = (const f32x4*)lutg;
        f32x4* dst = (f32x4*)lut;
#pragma unroll
        for (int q = 0; q < 8; ++q)
            dst[q * 256 + t] = src[q * 256 + t];
    }
    __syncthreads();

#pragma unroll
    for (int k = 0; k < RPT; ++k) {
        float xr[4] = {xv[k].x, xv[k].y, xv[k].z, xv[k].w};
        float xf[4]; bool ok[4];
#pragma unroll
        for (int e = 0; e < 4; ++e) {
            ok[e] = (xr[e] == xr[e]);                 // !isnan
            xf[e] = ok[e] ? xr[e] : 0.0f;
        }

        float num = 0.0f, den = 0.0f;
#pragma unroll
        for (int e = 0; e < 4; ++e) {
            // gating (wgl/bgl uniform s_loads; 1 SGPR operand per fma)
            float lg = fmaf(xf[0], gp[e * 4 + 0],
                       fmaf(xf[1], gp[e * 4 + 1],
                       fmaf(xf[2], gp[e * 4 + 2],
                       fmaf(xf[3], gp[e * 4 + 3], gp[16 + e]))));
            lg = ok[e] ? lg : -__builtin_inff();
            float p = __builtin_amdgcn_exp2f(lg);     // 0 if masked

            // PWL lookup: adj_e = max(m*xf + c, 0)
            int bi = (int)fmaf(xf[e], SCALE, 512.0f); // (xf-XLO)*SCALE
            bi = bi < 0 ? 0 : (bi > BINS - 1 ? BINS - 1 : bi);
            f32x2 mc = lut[e * BINS + bi];            // ds_read_b64
            float adj = fmaxf(fmaf(xf[e], mc.x, mc.y), 0.0f);

            den += p;
            num = fmaf(p, adj, num);
        }
        // den==0 only when all experts masked: num=0 -> 0*inf = NaN (matches ref)
        float res = num * __builtin_amdgcn_rcpf(den);
        __builtin_nontemporal_store(res, &out[base + k * 256]);
    }
}

extern "C" void kernel_launch(void* const* d_in, const int* in_sizes, int n_in,
                              void* d_out, int out_size, void* d_ws, size_t ws_size,
                              hipStream_t stream) {
    const f32x4* x  = (const f32x4*)d_in[0];
    const float* Wg = (const float*)d_in[1];
    const float* bg = (const float*)d_in[2];
    const float* W1 = (const float*)d_in[3];
    const float* b1 = (const float*)d_in[4];
    const float* W2 = (const float*)d_in[5];
    const float* b2 = (const float*)d_in[6];
    float* out = (float*)d_out;
    f32x2* lut = (f32x2*)d_ws;                 // 4*BINS*8B = 32 KB + 80 B gating

    prep_kernel<<<(4 * BINS + 255) / 256, 256, 0, stream>>>(Wg, bg, W1, b1, W2, b2, lut);

    int B = in_sizes[0] / 4;                   // 8388608 rows
    int blocks = B / (256 * RPT);              // 2048
    moe_kernel<<<blocks, 256, 0, stream>>>(x, lut, out);
}

// Round 12
// 34.880 us; speedup vs baseline: 1.0985x; 1.0985x over previous
//
#include <hip/hip_runtime.h>

// MixtureOfExpertsNet: B=8388608 rows, E=4, H=16. f32 in/out.
// pred = sum_e(p_e*m_e*adj_e) / sum_e(p_e*m_e)  (softmax max-sub and /wsum cancel)
//
// R10 proved the 58-74us plateau was VALU inst count: PWL-LUT body (~80
// slots/row) dropped 59.3 -> 35.6us. adj_e(x) is 1-D piecewise-linear ->
// midpoint-anchored (slope,intercept) LUT.
// R12 = R10 skeleton (RPT=8, 4096 blocks, plain stores) + two targeted trims:
//   - 512 bins (16 KB LUT): halves staging L2 traffic AND lifts the LDS
//     occupancy cap 5 -> 10 blocks/CU (20 -> 32 waves/CU) for latency hiding.
//     Error ~2x (absmax ~1.6e-2, threshold 4.4e-2).
//   - gating consts pre-scaled by log2e in prep (saves 4 v_mul/row).

typedef float f32x2 __attribute__((ext_vector_type(2)));
typedef float f32x4 __attribute__((ext_vector_type(4)));

#define RPT   8
#define BINS  512
#define SCALE 32.0f          // BINS / 16, domain [-8, 8]

// one thread per (e, bin): m = sum_{h active at bin midpoint} w1*w2,
//                          c = b2 + sum_{h active} b1*w2
// threads 0..19 of block 0 also write log2e-scaled gating consts after LUT.
__global__ __launch_bounds__(256) void prep_kernel(
    const float* __restrict__ Wg, const float* __restrict__ bg,
    const float* __restrict__ W1, const float* __restrict__ b1,
    const float* __restrict__ W2, const float* __restrict__ b2,
    f32x2* __restrict__ lut)      // [e*BINS + bin], then 16 wgl + 4 bgl floats
{
    int i = blockIdx.x * blockDim.x + threadIdx.x;   // 0 .. 4*BINS-1
    if (i >= 4 * BINS) return;
    int e = i / BINS, bin = i & (BINS - 1);
    float xc = ((float)bin + 0.5f) * (1.0f / SCALE) - 8.0f;   // bin midpoint
    float m = 0.0f, c = b2[e];
    for (int h = 0; h < 16; ++h) {
        float w1 = W1[e * 16 + h], bb = b1[e * 16 + h], w2 = W2[e * 16 + h];
        bool active = (fmaf(w1, xc, bb) > 0.0f);     // w1==0 case falls out
        m += active ? w1 * w2 : 0.0f;
        c += active ? bb * w2 : 0.0f;
    }
    lut[e * BINS + bin] = (f32x2){m, c};

    const float L2E = 1.4426950408889634f;
    float* gp = (float*)(lut + 4 * BINS);
    if (i < 16) gp[i] = Wg[i] * L2E;                 // wgl[e*4+j]
    else if (i < 20) gp[i] = bg[i - 16] * L2E;       // bgl[e]
}

__global__ __launch_bounds__(256) void moe_kernel(
    const f32x4* __restrict__ x, const f32x2* __restrict__ lutg,
    float* __restrict__ out)
{
    __shared__ f32x2 lut[4 * BINS];                  // 16 KB
    const int t = threadIdx.x;
    const int base = blockIdx.x * (256 * RPT) + t;
    const float* gp = (const float*)(lutg + 4 * BINS);  // uniform -> s_load

    // issue all row loads first; latency hides under LUT staging + barrier
    f32x4 xv[RPT];
#pragma unroll
    for (int k = 0; k < RPT; ++k)
        xv[k] = x[base + k * 256];

    // stage LUT (16KB, L2-resident) to LDS, coalesced
    {
        const f32x4* src = (const f32x4*)lutg;
        f32x4* dst = (f32x4*)lut;
#pragma unroll
        for (int q = 0; q < 4; ++q)
            dst[q * 256 + t] = src[q * 256 + t];
    }
    __syncthreads();

#pragma unroll
    for (int k = 0; k < RPT; ++k) {
        float xr[4] = {xv[k].x, xv[k].y, xv[k].z, xv[k].w};
        float xf[4]; bool ok[4];
#pragma unroll
        for (int e = 0; e < 4; ++e) {
            ok[e] = (xr[e] == xr[e]);                 // !isnan
            xf[e] = ok[e] ? xr[e] : 0.0f;
        }

        float num = 0.0f, den = 0.0f;
#pragma unroll
        for (int e = 0; e < 4; ++e) {
            // gating (wgl/bgl uniform s_loads; 1 SGPR operand per fma)
            float lg = fmaf(xf[0], gp[e * 4 + 0],
                       fmaf(xf[1], gp[e * 4 + 1],
                       fmaf(xf[2], gp[e * 4 + 2],
                       fmaf(xf[3], gp[e * 4 + 3], gp[16 + e]))));
            lg = ok[e] ? lg : -__builtin_inff();
            float p = __builtin_amdgcn_exp2f(lg);     // 0 if masked

            // PWL lookup: adj_e = max(m*xf + c, 0)
            int bi = (int)fmaf(xf[e], SCALE, (float)(BINS / 2));
            bi = bi < 0 ? 0 : (bi > BINS - 1 ? BINS - 1 : bi);
            f32x2 mc = lut[e * BINS + bi];            // ds_read_b64
            float adj = fmaxf(fmaf(xf[e], mc.x, mc.y), 0.0f);

            den += p;
            num = fmaf(p, adj, num);
        }
        // den==0 only when all experts masked: num=0 -> 0*inf = NaN (matches ref)
        out[base + k * 256] = num * __builtin_amdgcn_rcpf(den);
    }
}

extern "C" void kernel_launch(void* const* d_in, const int* in_sizes, int n_in,
                              void* d_out, int out_size, void* d_ws, size_t ws_size,
                              hipStream_t stream) {
    const f32x4* x  = (const f32x4*)d_in[0];
    const float* Wg = (const float*)d_in[1];
    const float* bg = (const float*)d_in[2];
    const float* W1 = (const float*)d_in[3];
    const float* b1 = (const float*)d_in[4];
    const float* W2 = (const float*)d_in[5];
    const float* b2 = (const float*)d_in[6];
    float* out = (float*)d_out;
    f32x2* lut = (f32x2*)d_ws;                 // 4*BINS*8B = 16 KB + 80 B gating

    prep_kernel<<<(4 * BINS + 255) / 256, 256, 0, stream>>>(Wg, bg, W1, b1, W2, b2, lut);

    int B = in_sizes[0] / 4;                   // 8388608 rows
    int blocks = B / (256 * RPT);              // 4096
    moe_kernel<<<blocks, 256, 0, stream>>>(x, lut, out);
}